// Round 5
// baseline (745.870 us; speedup 1.0000x reference)
//
#include <hip/hip_runtime.h>
#include <hip/hip_bf16.h>

using bf16x8 = short __attribute__((ext_vector_type(8)));
using f32x16 = float __attribute__((ext_vector_type(16)));

#define MROWS 100352      // 2048*49
#define SCALE_Q 0.17677669529663687f

static __device__ __forceinline__ unsigned short f2bs(float f){
  unsigned u = __builtin_bit_cast(unsigned, f);
  unsigned r = (u + 0x7FFFu + ((u >> 16) & 1u)) >> 16;   // RNE
  return (unsigned short)r;
}
static __device__ __forceinline__ unsigned packbf(float a, float b){
  return (unsigned)f2bs(a) | ((unsigned)f2bs(b) << 16);
}

// ---------------- x -> bf16 cast (each thread: 8 elems) ----------------
__global__ void k_xcast(const float* __restrict__ x, short* __restrict__ xb){
  const int i = blockIdx.x*256 + threadIdx.x;
  const float4 u0 = *reinterpret_cast<const float4*>(x + (size_t)i*8);
  const float4 u1 = *reinterpret_cast<const float4*>(x + (size_t)i*8 + 4);
  bf16x8 t;
  t[0]=(short)f2bs(u0.x); t[1]=(short)f2bs(u0.y); t[2]=(short)f2bs(u0.z); t[3]=(short)f2bs(u0.w);
  t[4]=(short)f2bs(u1.x); t[5]=(short)f2bs(u1.y); t[6]=(short)f2bs(u1.z); t[7]=(short)f2bs(u1.w);
  *reinterpret_cast<bf16x8*>(xb + (size_t)i*8) = t;
}

// ---------------- weight conversion (transposed, head-permuted, q-scaled) + bias table ----------------
__global__ void k_convert(const float* __restrict__ qkvW, const float* __restrict__ qkvB,
                          const float* __restrict__ projW, const float* __restrict__ ab,
                          short* __restrict__ WqkvT, short* __restrict__ WpT,
                          float* __restrict__ bqkv, float* __restrict__ bias_exp){
  int i = blockIdx.x*256 + threadIdx.x;
  if (i < 1536*384){
    int c = i/384, f = i - c*384;
    int src; float sc = 1.0f;
    if (c < 512){ src = (c>>6)*192 + (c&63); if ((c&63) < 32) sc = SCALE_Q; }
    else        { int dv = c - 512; src = (dv>>7)*192 + 64 + (dv&127); }
    WqkvT[i] = (short)f2bs(qkvW[f*1536 + src] * sc);
    return;
  }
  i -= 1536*384;
  if (i < 384*1024){
    int j = i/1024, m = i - j*1024;
    WpT[i] = (short)f2bs(projW[m*384 + j]);
    return;
  }
  i -= 384*1024;
  if (i < 1536){
    int c = i; int src; float sc = 1.0f;
    if (c < 512){ src = (c>>6)*192 + (c&63); if ((c&63) < 32) sc = SCALE_Q; }
    else        { int dv = c - 512; src = (dv>>7)*192 + 64 + (dv&127); }
    bqkv[c] = qkvB[src] * sc;
    return;
  }
  i -= 1536;
  if (i < 8*64*49){
    int h = i / (64*49), rem = i - h*(64*49);
    int r = rem / 49, n = rem - r*49;
    float v = 0.0f;
    if (r < 49){
      int rh = r/7, rw = r - rh*7, ch = n/7, cw = n - ch*7;
      int dh = rh>ch?rh-ch:ch-rh, dw = rw>cw?rw-cw:cw-rw;
      v = ab[h*49 + dh*7 + dw];
    }
    bias_exp[i] = v;
  }
}

// ---------------- LDS-staged qkv GEMM: tile 128x256, BK=64, 8 waves (2M x 4N) ----------------
template<int KTOT, int NT, int NSLAB, bool F32OUT>
__global__ __launch_bounds__(512) void k_gemm(const short* __restrict__ A,
                                              const short* __restrict__ Bw,
                                              const float* __restrict__ bias,
                                              void* __restrict__ Cout, int ldc){
  constexpr int BN = NT*128;
  __shared__ short Alds[128*64];
  __shared__ short Blds[BN*64];
  const int lane = threadIdx.x & 63, w = threadIdx.x >> 6;
  const int hi = lane >> 5, l31 = lane & 31;
  const int wm = w >> 2, wn = w & 3;

  const int nwg = NSLAB * 784;
  const int lin = blockIdx.x + NSLAB * blockIdx.y;
  const int swz = (lin & 7) * (nwg >> 3) + (lin >> 3);
  const int slab = swz % NSLAB, panel = swz / NSLAB;
  const size_t R0 = (size_t)panel * 128, C0 = (size_t)slab * BN;

  f32x16 acc[2][NT];
  #pragma unroll
  for (int mt=0; mt<2; ++mt)
    #pragma unroll
    for (int nt=0; nt<NT; ++nt) acc[mt][nt] = (f32x16)0.0f;

  const int srow = lane >> 3;
  const int sG   = ((lane & 7) ^ srow) * 8;
  const short* aG = A  + (R0 + (size_t)(w*8 + srow))*KTOT + sG;
  const short* bG = Bw + (C0 + (size_t)(w*8 + srow))*KTOT + sG;

  constexpr int NK = KTOT/64;
  for (int kt=0; kt<NK; ++kt){
    #pragma unroll
    for (int j=0; j<2; ++j)
      __builtin_amdgcn_global_load_lds(
        (const unsigned int __attribute__((address_space(1)))*)(aG + (size_t)j*64*KTOT + kt*64),
        (unsigned int __attribute__((address_space(3)))*)(&Alds[(j*64 + w*8)*64]), 16, 0, 0);
    #pragma unroll
    for (int j=0; j<2*NT; ++j)
      __builtin_amdgcn_global_load_lds(
        (const unsigned int __attribute__((address_space(1)))*)(bG + (size_t)j*64*KTOT + kt*64),
        (unsigned int __attribute__((address_space(3)))*)(&Blds[(j*64 + w*8)*64]), 16, 0, 0);
    __syncthreads();
    #pragma unroll
    for (int ks=0; ks<4; ++ks){
      bf16x8 aF[2], bF[NT];
      #pragma unroll
      for (int mt=0; mt<2; ++mt){
        const int rA = wm*64 + mt*32 + l31;
        aF[mt] = *reinterpret_cast<const bf16x8*>(
                   (const char*)Alds + rA*128 + ((((ks<<1)|hi) ^ (rA&7))<<4));
      }
      #pragma unroll
      for (int nt=0; nt<NT; ++nt){
        const int rB = wn*(NT*32) + nt*32 + l31;
        bF[nt] = *reinterpret_cast<const bf16x8*>(
                   (const char*)Blds + rB*128 + ((((ks<<1)|hi) ^ (rB&7))<<4));
      }
      #pragma unroll
      for (int mt=0; mt<2; ++mt)
        #pragma unroll
        for (int nt=0; nt<NT; ++nt)
          acc[mt][nt] = __builtin_amdgcn_mfma_f32_32x32x16_bf16(aF[mt], bF[nt], acc[mt][nt], 0,0,0);
    }
    __syncthreads();
  }

  #pragma unroll
  for (int nt=0; nt<NT; ++nt){
    const int c = (int)C0 + wn*(NT*32) + nt*32 + l31;
    const float bb = bias[c];
    #pragma unroll
    for (int mt=0; mt<2; ++mt){
      const size_t rbase = R0 + wm*64 + mt*32;
      #pragma unroll
      for (int rg=0; rg<16; ++rg){
        const size_t r = rbase + (rg&3) + 8*(rg>>2) + 4*hi;
        if constexpr (F32OUT) ((float*)Cout)[r*ldc + c] = acc[mt][nt][rg] + bb;
        else                  ((short*)Cout)[r*ldc + c] = (short)f2bs(acc[mt][nt][rg] + bb);
      }
    }
  }
}

// ---------------- fused attention + proj: block = batch, 512 thr, wave = head ----------------
// Phase 1: stage V (8 heads) into LDS [8][49][136] swizzled.
// Phase 2: per-wave swapped QK^T + in-register softmax + PV (results packed bf16 in regs).
// Phase 3: write PV out into SAME LDS as aout[49][1032]; Phase 4: 64x384 proj GEMM,
//          Wp streamed from global (L2-resident), fp32 out + bias.
__global__ __launch_bounds__(512) void k_attnproj(const short* __restrict__ qkvbuf,
                                                  const float* __restrict__ bias_exp,
                                                  const short* __restrict__ WpT,
                                                  const float* __restrict__ pb,
                                                  float* __restrict__ out){
  const int t = threadIdx.x;
  const int lane = t & 63, w = t >> 6;          // w = head (attn) / wave id (proj)
  const int hi = lane >> 5, l31 = lane & 31;
  const int b = blockIdx.x;
  const int h = w;

  __shared__ short lds[8*49*136];   // 106,624 B; reused as aout[49][1032] (101 KB) in proj phase

  // ---- Phase 1: stage V for all 8 heads ----
  {
    const int nidx = t >> 7;          // 0..3
    const int within = t & 127;       // covers 1024 v-cols, 8 per thread
    const int hh = within >> 4;
    const int d0 = ((within & 15) * 8) ^ (((0)&1) << 5); // recomputed per n below
    #pragma unroll
    for (int i=0; i<13; ++i){
      const int n = i*4 + nidx;
      if (n < 49){
        const bf16x8 vv = *reinterpret_cast<const bf16x8*>(qkvbuf + (b*49+n)*1536 + 512 + within*8);
        const int dd = ((within & 15) * 8) ^ (((n>>3)&1) << 5);
        *reinterpret_cast<bf16x8*>(&lds[(hh*49 + n)*136 + dd]) = vv;
      }
    }
    (void)d0;
  }

  // K fragments (A operand of S^T = K @ Q^T) — global, independent of LDS
  bf16x8 kf[2][2];
  #pragma unroll
  for (int mt=0; mt<2; ++mt){
    const int n = 32*mt + l31;
    #pragma unroll
    for (int ks=0; ks<2; ++ks)
      kf[mt][ks] = (n < 49)
        ? *reinterpret_cast<const bf16x8*>(qkvbuf + (b*49+n)*1536 + h*64 + 32 + ks*16 + hi*8)
        : (bf16x8)(short)0;
  }
  __syncthreads();

  const short* vb = &lds[h*49*136];
  const int dxbase = hi << 5;
  unsigned pko[2][4][8];   // packed bf16 PV results [rb][dt][rg-pair]

  // ---- Phase 2: per-head attention ----
  for (int rb=0; rb<2; ++rb){
    const int r = 32*rb + l31;
    bf16x8 qf[2];
    #pragma unroll
    for (int ks=0; ks<2; ++ks)
      qf[ks] = (r < 49)
        ? *reinterpret_cast<const bf16x8*>(qkvbuf + (b*49+r)*1536 + h*64 + ks*16 + hi*8)
        : (bf16x8)(short)0;

    f32x16 s[2];
    s[0] = (f32x16)0.0f; s[1] = (f32x16)0.0f;
    #pragma unroll
    for (int ks=0; ks<2; ++ks){
      s[0] = __builtin_amdgcn_mfma_f32_32x32x16_bf16(kf[0][ks], qf[ks], s[0], 0, 0, 0);
      s[1] = __builtin_amdgcn_mfma_f32_32x32x16_bf16(kf[1][ks], qf[ks], s[1], 0, 0, 0);
    }

    float mloc = -3.0e38f;
    #pragma unroll
    for (int mt=0; mt<2; ++mt)
      #pragma unroll
      for (int rg=0; rg<16; ++rg){
        const int n = 32*mt + (rg&3) + 8*(rg>>2) + 4*hi;
        float v = s[mt][rg];
        v = (n < 49) ? v + bias_exp[(h*64 + r)*49 + n] : -1.0e30f;
        s[mt][rg] = v;
        mloc = fmaxf(mloc, v);
      }
    const float mrow = fmaxf(mloc, __shfl_xor(mloc, 32));
    float sloc = 0.0f;
    #pragma unroll
    for (int mt=0; mt<2; ++mt)
      #pragma unroll
      for (int rg=0; rg<16; ++rg){
        const float p = __expf(s[mt][rg] - mrow);
        s[mt][rg] = p; sloc += p;
      }
    const float inv = 1.0f / (sloc + __shfl_xor(sloc, 32));
    #pragma unroll
    for (int mt=0; mt<2; ++mt)
      #pragma unroll
      for (int rg=0; rg<16; ++rg) s[mt][rg] *= inv;

    unsigned pk[8][2];
    #pragma unroll
    for (int o=0; o<8; ++o){
      const int mt = o>>2, base = 4*(o&3);
      pk[o][0] = packbf(s[mt][base+0], s[mt][base+1]);
      pk[o][1] = packbf(s[mt][base+2], s[mt][base+3]);
    }
    bf16x8 af[4];
    #pragma unroll
    for (int ks=0; ks<4; ++ks){
      const unsigned e0 = pk[2*ks][0],   e1 = pk[2*ks][1];
      const unsigned o0 = pk[2*ks+1][0], o1 = pk[2*ks+1][1];
      const unsigned own0 = hi ? o0 : e0, own1 = hi ? o1 : e1;
      const unsigned oth0 = hi ? e0 : o0, oth1 = hi ? e1 : o1;
      const unsigned sw0 = __shfl_xor(oth0, 32), sw1 = __shfl_xor(oth1, 32);
      const unsigned lo0 = hi ? sw0 : own0, lo1 = hi ? sw1 : own1;
      const unsigned h0  = hi ? own0 : sw0, h1  = hi ? own1 : sw1;
      union { bf16x8 v; unsigned u[4]; } tt;
      tt.u[0]=lo0; tt.u[1]=lo1; tt.u[2]=h0; tt.u[3]=h1;
      af[ks] = tt.v;
    }

    #pragma unroll
    for (int dt=0; dt<4; ++dt){
      const int dx = (dt*32 + l31) ^ dxbase;
      f32x16 acc = (f32x16)0.0f;
      #pragma unroll
      for (int ks=0; ks<4; ++ks){
        bf16x8 tt;
        if (ks < 3){
          const int nb = ks*16 + hi*8;
          #pragma unroll
          for (int j=0; j<8; ++j) tt[j] = vb[(nb + j)*136 + dx];
        } else {
          #pragma unroll
          for (int j=0; j<8; ++j) tt[j] = 0;
          if (hi == 0) tt[0] = vb[48*136 + (dt*32 + l31)];
        }
        acc = __builtin_amdgcn_mfma_f32_32x32x16_bf16(af[ks], tt, acc, 0, 0, 0);
      }
      #pragma unroll
      for (int j=0; j<8; ++j)
        pko[rb][dt][j] = packbf(acc[2*j], acc[2*j+1]);
    }
  }
  __syncthreads();   // all PV reads of V complete

  // ---- Phase 3: write aout[49][1032] bf16 into LDS (overwrites V region) ----
  #pragma unroll
  for (int rb=0; rb<2; ++rb)
    #pragma unroll
    for (int dt=0; dt<4; ++dt){
      const int dcol = h*128 + dt*32 + l31;
      #pragma unroll
      for (int j=0; j<8; ++j){
        const unsigned u = pko[rb][dt][j];
        const int row0 = 32*rb + ((2*j)&3) + 8*(j>>1) + 4*hi;
        if (row0 < 49)   lds[row0*1032 + dcol] = (short)(u & 0xFFFFu);
        if (row0+1 < 49) lds[(row0+1)*1032 + dcol] = (short)(u >> 16);
      }
    }
  __syncthreads();

  // ---- Phase 4: proj GEMM out[49][384] = aout[49][1024] @ Wp + pb ----
  {
    const int wm = w >> 2, wn = w & 3;          // 2 row-tiles x 4 col-groups (96 cols each)
    const int rA = (wm*32 + l31 > 48) ? 48 : (wm*32 + l31);   // clamp padded rows
    f32x16 acc[3];
    acc[0]=(f32x16)0.0f; acc[1]=(f32x16)0.0f; acc[2]=(f32x16)0.0f;
    for (int ks=0; ks<64; ++ks){
      const bf16x8 aF = *reinterpret_cast<const bf16x8*>(&lds[rA*1032 + ks*16 + hi*8]);
      #pragma unroll
      for (int nt=0; nt<3; ++nt){
        const int c = wn*96 + nt*32 + l31;
        const bf16x8 bF = *reinterpret_cast<const bf16x8*>(WpT + c*1024 + ks*16 + hi*8);
        acc[nt] = __builtin_amdgcn_mfma_f32_32x32x16_bf16(aF, bF, acc[nt], 0, 0, 0);
      }
    }
    #pragma unroll
    for (int nt=0; nt<3; ++nt){
      const int c = wn*96 + nt*32 + l31;
      const float bb = pb[c];
      #pragma unroll
      for (int rg=0; rg<16; ++rg){
        const int r = wm*32 + (rg&3) + 8*(rg>>2) + 4*hi;
        if (r < 49)
          out[((size_t)b*49 + r)*384 + c] = acc[nt][rg] + bb;
      }
    }
  }
}

extern "C" void kernel_launch(void* const* d_in, const int* in_sizes, int n_in,
                              void* d_out, int out_size, void* d_ws, size_t ws_size,
                              hipStream_t stream) {
  const float* x     = (const float*)d_in[0];
  const float* qkvW  = (const float*)d_in[1];
  const float* qkvB  = (const float*)d_in[2];
  const float* projW = (const float*)d_in[3];
  const float* projB = (const float*)d_in[4];
  const float* ab    = (const float*)d_in[5];

  char* ws = (char*)d_ws;
  short* xb    = (short*)ws;
  size_t off = (size_t)MROWS*1024*2;
  short* qkvbuf = (short*)(ws + off); off += (size_t)MROWS*1536*2;
  short* WqkvT  = (short*)(ws + off); off += (size_t)1536*384*2;
  short* WpT    = (short*)(ws + off); off += (size_t)384*1024*2;
  float* bqkv   = (float*)(ws + off); off += (size_t)1536*4;
  float* bias_exp = (float*)(ws + off); off += (size_t)8*64*49*4;
  if (ws_size < off) return;

  const int conv_total = 1536*384 + 384*1024 + 1536 + 8*64*49;
  k_convert<<<(conv_total + 255)/256, 256, 0, stream>>>(qkvW, qkvB, projW, ab,
                                                        WqkvT, WpT, bqkv, bias_exp);
  k_xcast<<<MROWS*384/8/256, 256, 0, stream>>>(x, xb);
  k_gemm<384, 2, 6, false><<<dim3(6, 784), 512, 0, stream>>>(xb, WqkvT, bqkv, qkvbuf, 1536);
  k_attnproj<<<2048, 512, 0, stream>>>(qkvbuf, bias_exp, WpT, projB, (float*)d_out);
}

// Round 6
// 498.963 us; speedup vs baseline: 1.4948x; 1.4948x over previous
//
#include <hip/hip_runtime.h>
#include <hip/hip_bf16.h>

using bf16x8 = short __attribute__((ext_vector_type(8)));
using f32x16 = float __attribute__((ext_vector_type(16)));

#define MROWS 100352      // 2048*49
#define SCALE_Q 0.17677669529663687f

static __device__ __forceinline__ unsigned short f2bs(float f){
  unsigned u = __builtin_bit_cast(unsigned, f);
  unsigned r = (u + 0x7FFFu + ((u >> 16) & 1u)) >> 16;   // RNE
  return (unsigned short)r;
}
static __device__ __forceinline__ unsigned packbf(float a, float b){
  return (unsigned)f2bs(a) | ((unsigned)f2bs(b) << 16);
}

// ---------------- x -> bf16 cast (each thread: 8 elems) ----------------
__global__ void k_xcast(const float* __restrict__ x, short* __restrict__ xb){
  const int i = blockIdx.x*256 + threadIdx.x;
  const float4 u0 = *reinterpret_cast<const float4*>(x + (size_t)i*8);
  const float4 u1 = *reinterpret_cast<const float4*>(x + (size_t)i*8 + 4);
  bf16x8 t;
  t[0]=(short)f2bs(u0.x); t[1]=(short)f2bs(u0.y); t[2]=(short)f2bs(u0.z); t[3]=(short)f2bs(u0.w);
  t[4]=(short)f2bs(u1.x); t[5]=(short)f2bs(u1.y); t[6]=(short)f2bs(u1.z); t[7]=(short)f2bs(u1.w);
  *reinterpret_cast<bf16x8*>(xb + (size_t)i*8) = t;
}

// ---------------- weight conversion (transposed, head-permuted, q-scaled) + bias table ----------------
__global__ void k_convert(const float* __restrict__ qkvW, const float* __restrict__ qkvB,
                          const float* __restrict__ projW, const float* __restrict__ ab,
                          short* __restrict__ WqkvT, short* __restrict__ WpT,
                          float* __restrict__ bqkv, float* __restrict__ bias_exp){
  int i = blockIdx.x*256 + threadIdx.x;
  if (i < 1536*384){
    int c = i/384, f = i - c*384;
    int src; float sc = 1.0f;
    if (c < 512){ src = (c>>6)*192 + (c&63); if ((c&63) < 32) sc = SCALE_Q; }
    else        { int dv = c - 512; src = (dv>>7)*192 + 64 + (dv&127); }
    WqkvT[i] = (short)f2bs(qkvW[f*1536 + src] * sc);
    return;
  }
  i -= 1536*384;
  if (i < 384*1024){
    int j = i/1024, m = i - j*1024;
    WpT[i] = (short)f2bs(projW[m*384 + j]);
    return;
  }
  i -= 384*1024;
  if (i < 1536){
    int c = i; int src; float sc = 1.0f;
    if (c < 512){ src = (c>>6)*192 + (c&63); if ((c&63) < 32) sc = SCALE_Q; }
    else        { int dv = c - 512; src = (dv>>7)*192 + 64 + (dv&127); }
    bqkv[c] = qkvB[src] * sc;
    return;
  }
  i -= 1536;
  if (i < 8*64*49){
    int h = i / (64*49), rem = i - h*(64*49);
    int r = rem / 49, n = rem - r*49;
    float v = 0.0f;
    if (r < 49){
      int rh = r/7, rw = r - rh*7, ch = n/7, cw = n - ch*7;
      int dh = rh>ch?rh-ch:ch-rh, dw = rw>cw?rw-cw:cw-rw;
      v = ab[h*49 + dh*7 + dw];
    }
    bias_exp[i] = v;
  }
}

// ---------------- qkv GEMM: tile 128x256, BK=64, 8 waves (2M x 4N), XCD-chunked swizzle ----------------
template<int KTOT, int NT, int NSLAB, bool F32OUT>
__global__ __launch_bounds__(512) void k_gemm(const short* __restrict__ A,
                                              const short* __restrict__ Bw,
                                              const float* __restrict__ bias,
                                              void* __restrict__ Cout, int ldc){
  constexpr int BN = NT*128;
  __shared__ short Alds[128*64];
  __shared__ short Blds[BN*64];
  const int lane = threadIdx.x & 63, w = threadIdx.x >> 6;
  const int hi = lane >> 5, l31 = lane & 31;
  const int wm = w >> 2, wn = w & 3;

  const int nwg = NSLAB * 784;
  const int lin = blockIdx.x + NSLAB * blockIdx.y;
  const int swz = (lin & 7) * (nwg >> 3) + (lin >> 3);
  const int slab = swz % NSLAB, panel = swz / NSLAB;
  const size_t R0 = (size_t)panel * 128, C0 = (size_t)slab * BN;

  f32x16 acc[2][NT];
  #pragma unroll
  for (int mt=0; mt<2; ++mt)
    #pragma unroll
    for (int nt=0; nt<NT; ++nt) acc[mt][nt] = (f32x16)0.0f;

  const int srow = lane >> 3;
  const int sG   = ((lane & 7) ^ srow) * 8;
  const short* aG = A  + (R0 + (size_t)(w*8 + srow))*KTOT + sG;
  const short* bG = Bw + (C0 + (size_t)(w*8 + srow))*KTOT + sG;

  constexpr int NK = KTOT/64;
  for (int kt=0; kt<NK; ++kt){
    #pragma unroll
    for (int j=0; j<2; ++j)
      __builtin_amdgcn_global_load_lds(
        (const unsigned int __attribute__((address_space(1)))*)(aG + (size_t)j*64*KTOT + kt*64),
        (unsigned int __attribute__((address_space(3)))*)(&Alds[(j*64 + w*8)*64]), 16, 0, 0);
    #pragma unroll
    for (int j=0; j<2*NT; ++j)
      __builtin_amdgcn_global_load_lds(
        (const unsigned int __attribute__((address_space(1)))*)(bG + (size_t)j*64*KTOT + kt*64),
        (unsigned int __attribute__((address_space(3)))*)(&Blds[(j*64 + w*8)*64]), 16, 0, 0);
    __syncthreads();
    #pragma unroll
    for (int ks=0; ks<4; ++ks){
      bf16x8 aF[2], bF[NT];
      #pragma unroll
      for (int mt=0; mt<2; ++mt){
        const int rA = wm*64 + mt*32 + l31;
        aF[mt] = *reinterpret_cast<const bf16x8*>(
                   (const char*)Alds + rA*128 + ((((ks<<1)|hi) ^ (rA&7))<<4));
      }
      #pragma unroll
      for (int nt=0; nt<NT; ++nt){
        const int rB = wn*(NT*32) + nt*32 + l31;
        bF[nt] = *reinterpret_cast<const bf16x8*>(
                   (const char*)Blds + rB*128 + ((((ks<<1)|hi) ^ (rB&7))<<4));
      }
      #pragma unroll
      for (int mt=0; mt<2; ++mt)
        #pragma unroll
        for (int nt=0; nt<NT; ++nt)
          acc[mt][nt] = __builtin_amdgcn_mfma_f32_32x32x16_bf16(aF[mt], bF[nt], acc[mt][nt], 0,0,0);
    }
    __syncthreads();
  }

  #pragma unroll
  for (int nt=0; nt<NT; ++nt){
    const int c = (int)C0 + wn*(NT*32) + nt*32 + l31;
    const float bb = bias[c];
    #pragma unroll
    for (int mt=0; mt<2; ++mt){
      const size_t rbase = R0 + wm*64 + mt*32;
      #pragma unroll
      for (int rg=0; rg<16; ++rg){
        const size_t r = rbase + (rg&3) + 8*(rg>>2) + 4*hi;
        if constexpr (F32OUT) ((float*)Cout)[r*ldc + c] = acc[mt][nt][rg] + bb;
        else                  ((short*)Cout)[r*ldc + c] = (short)f2bs(acc[mt][nt][rg] + bb);
      }
    }
  }
}

// ---------------- proj GEMM: tile 128x128, BK=64, 4 waves (2x2), 3 slabs, chunked swizzle ----------------
// Swizzle puts the 3 column-slabs of one row-panel CONSECUTIVE on one XCD -> A panel fetched ~once.
__global__ __launch_bounds__(256) void k_proj4(const short* __restrict__ A,
                                               const short* __restrict__ Bw,
                                               const float* __restrict__ bias,
                                               float* __restrict__ out){
  __shared__ short Alds[128*64];
  __shared__ short Blds[128*64];
  const int lane = threadIdx.x & 63, w = threadIdx.x >> 6;
  const int hi = lane >> 5, l31 = lane & 31;
  const int wm = w >> 1, wn = w & 1;

  const int nwg = 3 * 784;                       // 2352, %8==0
  const int lin = blockIdx.x + 3 * blockIdx.y;
  const int swz = (lin & 7) * (nwg >> 3) + (lin >> 3);
  const int slab = swz % 3, panel = swz / 3;     // slab fastest within an XCD chunk
  const size_t R0 = (size_t)panel * 128, C0 = (size_t)slab * 128;

  f32x16 acc[2][2];
  acc[0][0]=(f32x16)0.f; acc[0][1]=(f32x16)0.f; acc[1][0]=(f32x16)0.f; acc[1][1]=(f32x16)0.f;

  const int srow = lane >> 3;                    // 256 thr: one gload instr covers 32 rows
  const int sG   = ((lane & 7) ^ srow) * 8;
  const short* aG = A  + (R0 + (size_t)(w*8 + srow))*1024 + sG;
  const short* bG = Bw + (C0 + (size_t)(w*8 + srow))*1024 + sG;

  for (int kt=0; kt<16; ++kt){
    #pragma unroll
    for (int j=0; j<4; ++j){
      __builtin_amdgcn_global_load_lds(
        (const unsigned int __attribute__((address_space(1)))*)(aG + (size_t)j*32*1024 + kt*64),
        (unsigned int __attribute__((address_space(3)))*)(&Alds[(j*32 + w*8)*64]), 16, 0, 0);
      __builtin_amdgcn_global_load_lds(
        (const unsigned int __attribute__((address_space(1)))*)(bG + (size_t)j*32*1024 + kt*64),
        (unsigned int __attribute__((address_space(3)))*)(&Blds[(j*32 + w*8)*64]), 16, 0, 0);
    }
    __syncthreads();
    #pragma unroll
    for (int ks=0; ks<4; ++ks){
      bf16x8 aF[2], bF[2];
      #pragma unroll
      for (int mt=0; mt<2; ++mt){
        const int rA = wm*64 + mt*32 + l31;
        aF[mt] = *reinterpret_cast<const bf16x8*>(
                   (const char*)Alds + rA*128 + ((((ks<<1)|hi) ^ (rA&7))<<4));
      }
      #pragma unroll
      for (int nt=0; nt<2; ++nt){
        const int rB = wn*64 + nt*32 + l31;
        bF[nt] = *reinterpret_cast<const bf16x8*>(
                   (const char*)Blds + rB*128 + ((((ks<<1)|hi) ^ (rB&7))<<4));
      }
      #pragma unroll
      for (int mt=0; mt<2; ++mt)
        #pragma unroll
        for (int nt=0; nt<2; ++nt)
          acc[mt][nt] = __builtin_amdgcn_mfma_f32_32x32x16_bf16(aF[mt], bF[nt], acc[mt][nt], 0,0,0);
    }
    __syncthreads();
  }

  #pragma unroll
  for (int nt=0; nt<2; ++nt){
    const int c = (int)C0 + wn*64 + nt*32 + l31;
    const float bb = bias[c];
    #pragma unroll
    for (int mt=0; mt<2; ++mt){
      const size_t rbase = R0 + wm*64 + mt*32;
      #pragma unroll
      for (int rg=0; rg<16; ++rg){
        const size_t r = rbase + (rg&3) + 8*(rg>>2) + 4*hi;
        out[r*384 + c] = acc[mt][nt][rg] + bb;
      }
    }
  }
}

// ---------------- attention: block = (batch, 4 heads), 256 thr; V staged in LDS (swizzled) ----------------
__global__ __launch_bounds__(256) void k_attn(const short* __restrict__ qkvbuf,
                                              const float* __restrict__ bias_exp, short* __restrict__ aout){
  const int lane = threadIdx.x & 63, w = threadIdx.x >> 6;
  const int hi = lane >> 5, l31 = lane & 31;
  const int b = blockIdx.x, hg = blockIdx.y;
  const int h = hg*4 + w;

  __shared__ short vlds[4*49*136];   // 53,312 B

  for (int i=0; i<13; ++i){
    const int n = i*4 + w;
    if (n < 49){
      const bf16x8 vv = *reinterpret_cast<const bf16x8*>(qkvbuf + (b*49+n)*1536 + 512 + hg*512 + lane*8);
      const int hh = lane >> 4;
      const int d0 = ((lane & 15) * 8) ^ (((n>>3)&1) << 5);
      *reinterpret_cast<bf16x8*>(&vlds[(hh*49 + n)*136 + d0]) = vv;
    }
  }
  __syncthreads();

  bf16x8 kf[2][2];
  #pragma unroll
  for (int mt=0; mt<2; ++mt){
    const int n = 32*mt + l31;
    #pragma unroll
    for (int ks=0; ks<2; ++ks)
      kf[mt][ks] = (n < 49)
        ? *reinterpret_cast<const bf16x8*>(qkvbuf + (b*49+n)*1536 + h*64 + 32 + ks*16 + hi*8)
        : (bf16x8)(short)0;
  }
  const short* vb = &vlds[w*49*136];
  const int dxbase = hi << 5;

  for (int rb=0; rb<2; ++rb){
    const int r = 32*rb + l31;
    bf16x8 qf[2];
    #pragma unroll
    for (int ks=0; ks<2; ++ks)
      qf[ks] = (r < 49)
        ? *reinterpret_cast<const bf16x8*>(qkvbuf + (b*49+r)*1536 + h*64 + ks*16 + hi*8)
        : (bf16x8)(short)0;

    f32x16 s[2];
    s[0] = (f32x16)0.0f; s[1] = (f32x16)0.0f;
    #pragma unroll
    for (int ks=0; ks<2; ++ks){
      s[0] = __builtin_amdgcn_mfma_f32_32x32x16_bf16(kf[0][ks], qf[ks], s[0], 0, 0, 0);
      s[1] = __builtin_amdgcn_mfma_f32_32x32x16_bf16(kf[1][ks], qf[ks], s[1], 0, 0, 0);
    }

    float mloc = -3.0e38f;
    #pragma unroll
    for (int mt=0; mt<2; ++mt)
      #pragma unroll
      for (int rg=0; rg<16; ++rg){
        const int n = 32*mt + (rg&3) + 8*(rg>>2) + 4*hi;
        float v = s[mt][rg];
        v = (n < 49) ? v + bias_exp[(h*64 + r)*49 + n] : -1.0e30f;
        s[mt][rg] = v;
        mloc = fmaxf(mloc, v);
      }
    const float mrow = fmaxf(mloc, __shfl_xor(mloc, 32));
    float sloc = 0.0f;
    #pragma unroll
    for (int mt=0; mt<2; ++mt)
      #pragma unroll
      for (int rg=0; rg<16; ++rg){
        const float p = __expf(s[mt][rg] - mrow);
        s[mt][rg] = p; sloc += p;
      }
    const float inv = 1.0f / (sloc + __shfl_xor(sloc, 32));
    #pragma unroll
    for (int mt=0; mt<2; ++mt)
      #pragma unroll
      for (int rg=0; rg<16; ++rg) s[mt][rg] *= inv;

    unsigned pk[8][2];
    #pragma unroll
    for (int o=0; o<8; ++o){
      const int mt = o>>2, base = 4*(o&3);
      pk[o][0] = packbf(s[mt][base+0], s[mt][base+1]);
      pk[o][1] = packbf(s[mt][base+2], s[mt][base+3]);
    }
    bf16x8 af[4];
    #pragma unroll
    for (int ks=0; ks<4; ++ks){
      const unsigned e0 = pk[2*ks][0],   e1 = pk[2*ks][1];
      const unsigned o0 = pk[2*ks+1][0], o1 = pk[2*ks+1][1];
      const unsigned own0 = hi ? o0 : e0, own1 = hi ? o1 : e1;
      const unsigned oth0 = hi ? e0 : o0, oth1 = hi ? e1 : o1;
      const unsigned sw0 = __shfl_xor(oth0, 32), sw1 = __shfl_xor(oth1, 32);
      const unsigned lo0 = hi ? sw0 : own0, lo1 = hi ? sw1 : own1;
      const unsigned h0  = hi ? own0 : sw0, h1  = hi ? own1 : sw1;
      union { bf16x8 v; unsigned u[4]; } t;
      t.u[0]=lo0; t.u[1]=lo1; t.u[2]=h0; t.u[3]=h1;
      af[ks] = t.v;
    }

    #pragma unroll
    for (int dt=0; dt<4; ++dt){
      const int dx = (dt*32 + l31) ^ dxbase;
      f32x16 acc = (f32x16)0.0f;
      #pragma unroll
      for (int ks=0; ks<4; ++ks){
        bf16x8 t;
        if (ks < 3){
          const int nb = ks*16 + hi*8;
          #pragma unroll
          for (int j=0; j<8; ++j) t[j] = vb[(nb + j)*136 + dx];
        } else {
          #pragma unroll
          for (int j=0; j<8; ++j) t[j] = 0;
          if (hi == 0) t[0] = vb[48*136 + (dt*32 + l31)];
        }
        acc = __builtin_amdgcn_mfma_f32_32x32x16_bf16(af[ks], t, acc, 0, 0, 0);
      }
      #pragma unroll
      for (int rg=0; rg<16; ++rg){
        const int rr = 32*rb + (rg&3) + 8*(rg>>2) + 4*hi;
        if (rr < 49)
          aout[(b*49+rr)*1024 + h*128 + dt*32 + l31] = (short)f2bs(acc[rg]);
      }
    }
  }
}

extern "C" void kernel_launch(void* const* d_in, const int* in_sizes, int n_in,
                              void* d_out, int out_size, void* d_ws, size_t ws_size,
                              hipStream_t stream) {
  const float* x     = (const float*)d_in[0];
  const float* qkvW  = (const float*)d_in[1];
  const float* qkvB  = (const float*)d_in[2];
  const float* projW = (const float*)d_in[3];
  const float* projB = (const float*)d_in[4];
  const float* ab    = (const float*)d_in[5];

  char* ws = (char*)d_ws;
  // xb (77 MB) aliased under aoutb (205.5 MB) — xb dead before k_attn writes aoutb
  short* aoutb = (short*)ws;
  short* xb    = (short*)ws;
  size_t off = (size_t)MROWS*1024*2;
  short* qkvbuf = (short*)(ws + off); off += (size_t)MROWS*1536*2;
  short* WqkvT  = (short*)(ws + off); off += (size_t)1536*384*2;
  short* WpT    = (short*)(ws + off); off += (size_t)384*1024*2;
  float* bqkv   = (float*)(ws + off); off += (size_t)1536*4;
  float* bias_exp = (float*)(ws + off); off += (size_t)8*64*49*4;
  if (ws_size < off) return;

  const int conv_total = 1536*384 + 384*1024 + 1536 + 8*64*49;
  k_convert<<<(conv_total + 255)/256, 256, 0, stream>>>(qkvW, qkvB, projW, ab,
                                                        WqkvT, WpT, bqkv, bias_exp);
  k_xcast<<<MROWS*384/8/256, 256, 0, stream>>>(x, xb);
  k_gemm<384, 2, 6, false><<<dim3(6, 784), 512, 0, stream>>>(xb, WqkvT, bqkv, qkvbuf, 1536);
  k_attn<<<dim3(2048, 2), 256, 0, stream>>>(qkvbuf, bias_exp, aoutb);
  k_proj4<<<dim3(3, 784), 256, 0, stream>>>(aoutb, WpT, projB, (float*)d_out);
}